// Round 5
// baseline (429.546 us; speedup 1.0000x reference)
//
#include <hip/hip_runtime.h>

#define D      8192
#define K      1024
#define BLOCK  256
#define GRID_MAX 2048
#define SCALE  0.011048543456039806f   // 1/sqrt(8192)

// ---------------------------------------------------------------------------
// Barrier-free wave-quarter FWHT.  H_8192 = H_4 (bits b11,b12) ⊗ H_2048.
// Block = 4 waves; wave w builds output segment w:
//   y_w[p] = sum_k sign(w, idx_k>>11) * u_k  at p = idx_k & 2047   (8 KB quarter)
//   out[row*8192 + w*2048 + :] = (1/sqrt(D)) * H_2048 y_w
// All LDS ops of a wave hit ONLY its own quarter -> same-wave in-order LDS
// semantics make the whole row pipeline barrier-free (0 __syncthreads).
//
// H_2048 stages: fwht32 on b0..b4 (regs) -> wave-private transpose ->
// fwht32 on b5..b9 (regs) -> b10 butterfly via DPP quad_perm(1,0,3,2) (lane^1).
//
// Quarter layouts (word = f32 index in quarter, p = logical 11-bit index):
//   L0: word = 4*swz(p>>2) + (p&3),  swz(f) = f ^ ((f>>3)&7)
//       scatter: random atomics (bijective swizzle). P1 read: lane l reads f4
//       phys4 = 8l + (g ^ (l&7))  -> bank-quad g^(l&7): 8 lanes/quad = free.
//   L1: logical R = (j<<6)|l  (j = b0..b4 post-P1, l = old lane = b5..b10),
//       same swz on R.  P1 write: word = 4*((f)^((2j+(l>>5))&7)) + (l&3),
//       f = (j<<4)+(l>>2): covers all 32 banks 2x per instr = free.
//       P2 read: same phys4 = 8l' + (k ^ (l'&7)) pattern = free.
//       New lane l' bits: bit0 = b10 (-> DPP xor-1), bits1..5 = b0..b4.
//       Regs m = b5..b9.
//   Store: p = ((l'&1)<<10) | (m<<5) | (l'>>1).  Per instr (fixed m): even
//       lanes -> 32 consecutive words, odd lanes -> 32 consecutive words
//       = 2 x 128B full sectors, NT-safe.
// ---------------------------------------------------------------------------

__device__ __forceinline__ void fwht32(float* x) {
#pragma unroll
    for (int s = 0; s < 5; ++s) {
        const int h = 1 << s;
#pragma unroll
        for (int g = 0; g < 32; g += 2 * h)
#pragma unroll
            for (int e = 0; e < h; ++e) {
                float a = x[g + e], b = x[g + e + h];
                x[g + e]     = a + b;
                x[g + e + h] = a - b;
            }
    }
}

// returns x[lane^1] + sgn*x[lane]   (DPP quad_perm [1,0,3,2] = 0xB1, VALU-only)
__device__ __forceinline__ float bfly_xor1(float x, float sgn) {
    const int yi = __builtin_amdgcn_mov_dpp(__float_as_int(x), 0xB1, 0xF, 0xF, true);
    return __builtin_fmaf(sgn, x, __int_as_float(yi));
}

__global__ __launch_bounds__(BLOCK, 5)
void UpProjectFastHadamardTransform_80101140070867_kernel(
    const float* __restrict__ u, const int* __restrict__ idx,
    float* __restrict__ out, int nrows)
{
    __shared__ float lds[D];               // 4 quarters x 2048 f32 = 32 KB
    const int T = threadIdx.x;
    const int w = T >> 6;                  // wave id = output segment
    const int l = T & 63;

    float*  q  = lds + (w << 11);          // own quarter
    float4* q4 = (float4*)q;

    // ---- prologue (once per block): pack scatter descriptors ----
    // pk = phys word (11 bits) | signflip<<31,  sign = popcount2(w & (i>>11))
    int pk[16];
    {
        const int4* idx4 = (const int4*)idx;
#pragma unroll
        for (int j = 0; j < 4; ++j) {
            const int4 id = idx4[(l << 2) + j];
            auto PACK = [&](int i) {
                const int p = i & 2047, f = p >> 2;
                const int word = 4 * (f ^ ((f >> 3) & 7)) + (p & 3);
                const int sb = (i >> 11) & w;
                return word | (((sb ^ (sb >> 1)) & 1) << 31);
            };
            pk[4*j+0] = PACK(id.x); pk[4*j+1] = PACK(id.y);
            pk[4*j+2] = PACK(id.z); pk[4*j+3] = PACK(id.w);
        }
    }

    int r = blockIdx.x;
    const int stride = (int)gridDim.x;

    float4 uv[4];                          // current row's u (matches pk order)
    {
        const float4* u4 = (const float4*)(u + (size_t)r * K);
#pragma unroll
        for (int j = 0; j < 4; ++j) uv[j] = u4[(l << 2) + j];
    }

    const int   c1  = l & 7;               // swz xor for phase reads
    const float sgn = (l & 1) ? -1.f : 1.f;

    while (r < nrows) {
        // zero own quarter (wave-private; same-wave LDS ops are in order)
#pragma unroll
        for (int j = 0; j < 8; ++j)
            q4[(j << 6) + l] = make_float4(0.f, 0.f, 0.f, 0.f);

        // scatter: 16 signed atomics into own quarter (all 1024 row values)
#pragma unroll
        for (int j = 0; j < 4; ++j) {
            const int p0 = pk[4*j+0], p1 = pk[4*j+1],
                      p2 = pk[4*j+2], p3 = pk[4*j+3];
            atomicAdd(&q[p0 & 2047], __int_as_float(__float_as_int(uv[j].x) ^ (p0 & 0x80000000)));
            atomicAdd(&q[p1 & 2047], __int_as_float(__float_as_int(uv[j].y) ^ (p1 & 0x80000000)));
            atomicAdd(&q[p2 & 2047], __int_as_float(__float_as_int(uv[j].z) ^ (p2 & 0x80000000)));
            atomicAdd(&q[p3 & 2047], __int_as_float(__float_as_int(uv[j].w) ^ (p3 & 0x80000000)));
        }

        // prefetch next row's u (reuses uv regs; latency hidden under P1/P2)
        const int rn = r + stride;
        if (rn < nrows) {
            const float4* u4 = (const float4*)(u + (size_t)rn * K);
#pragma unroll
            for (int j = 0; j < 4; ++j) uv[j] = u4[(l << 2) + j];
        }

        float x[32];

        // ---- P1: read own quarter, fwht32 over b0..b4 ----
#pragma unroll
        for (int g = 0; g < 8; ++g) {
            const float4 a = q4[(l << 3) + (g ^ c1)];
            x[4*g+0] = a.x; x[4*g+1] = a.y; x[4*g+2] = a.z; x[4*g+3] = a.w;
        }
        fwht32(x);

        // ---- transposed write -> L1 (wave-private, conflict-free) ----
#pragma unroll
        for (int j = 0; j < 32; ++j) {
            const int f = (j << 4) + (l >> 2);
            q[4 * (f ^ ((2 * j + (l >> 5)) & 7)) + (l & 3)] = x[j];
        }

        // ---- P2: read back (same swz pattern), fwht32 over b5..b9 ----
#pragma unroll
        for (int g = 0; g < 8; ++g) {
            const float4 a = q4[(l << 3) + (g ^ c1)];
            x[4*g+0] = a.x; x[4*g+1] = a.y; x[4*g+2] = a.z; x[4*g+3] = a.w;
        }
        fwht32(x);

        // ---- b10 butterfly (DPP lane^1, pure VALU) + scaled NT store ----
        float* orow = out + (size_t)r * D + (w << 11) + ((l & 1) << 10) + (l >> 1);
#pragma unroll
        for (int m = 0; m < 32; ++m) {
            const float t = bfly_xor1(x[m], sgn);
            __builtin_nontemporal_store(t * SCALE, orow + (m << 5));
        }

        r = rn;
    }
}

extern "C" void kernel_launch(void* const* d_in, const int* in_sizes, int n_in,
                              void* d_out, int out_size, void* d_ws, size_t ws_size,
                              hipStream_t stream) {
    const float* u   = (const float*)d_in[0];
    const int*   idx = (const int*)d_in[1];
    float*       out = (float*)d_out;
    const int rows = in_sizes[0] / K;   // 8192
    const int grid = rows < GRID_MAX ? rows : GRID_MAX;
    hipLaunchKernelGGL(UpProjectFastHadamardTransform_80101140070867_kernel,
                       dim3(grid), dim3(BLOCK), 0, stream, u, idx, out, rows);
}

// Round 6
// 420.491 us; speedup vs baseline: 1.0215x; 1.0215x over previous
//
#include <hip/hip_runtime.h>

#define D      8192
#define K      1024
#define BLOCK  256
#define GRID_MAX 2048
#define SCALE  0.011048543456039806f   // 1/sqrt(8192)

// ---------------------------------------------------------------------------
// Barrier-free wave-quarter FWHT.  H_8192 = H_4 (bits b11,b12) ⊗ H_2048.
// Block = 4 waves; wave w builds output segment w:
//   y_w[p] = sum_k sign(w, idx_k>>11) * u_k  at p = idx_k & 2047   (8 KB quarter)
//   out[row*8192 + w*2048 + :] = (1/sqrt(D)) * H_2048 y_w
// All LDS ops of a wave hit ONLY its own quarter -> same-wave in-order LDS
// semantics make the whole row pipeline barrier-free (0 __syncthreads).
//
// ROUND-6 CHANGE (spill fix): __launch_bounds__(256, 4).  With (256,5) the
// allocator pinned every variant at 48 VGPRs (driving toward 8 waves/EU) and
// spilled pk/uv/x to scratch: rounds 3/5 showed +50..100 MB on BOTH
// FETCH_SIZE and WRITE_SIZE and 176/212 us kernels.  Occupancy is LDS-bound
// at 5 blocks/CU (32 KB) either way, so regs <=128 are free.
// Also: idx/u loads reordered to [j*64 + l] so each load instruction is one
// contiguous 1 KB wave access.
//
// Quarter layouts (word = f32 index in quarter, p = logical 11-bit index):
//   L0: word = 4*swz(p>>2) + (p&3),  swz(f) = f ^ ((f>>3)&7)
//       scatter: random atomics (bijective swizzle). P1 read: lane l reads f4
//       phys4 = 8l + (g ^ (l&7))  -> bank-quad g^(l&7): 8 lanes/quad = free.
//   L1: logical R = (j<<6)|l  (j = b0..b4 post-P1, l = old lane = b5..b10),
//       same swz on R.  P1 write: word = 4*(f^((2j+(l>>5))&7)) + (l&3),
//       f = (j<<4)+(l>>2): covers all 32 banks 2x per instr = free.
//       P2 read: same phys4 = 8l' + (k ^ (l'&7)) pattern = free.
//       New lane l' bits: bit0 = b10 (-> DPP xor-1), bits1..5 = b0..b4.
//       Regs m = b5..b9.
//   Store: p = ((l'&1)<<10) | (m<<5) | (l'>>1).  Per instr (fixed m): even
//       lanes -> 128 B contiguous, odd lanes -> 128 B contiguous (NT-safe).
// ---------------------------------------------------------------------------

__device__ __forceinline__ void fwht32(float* x) {
#pragma unroll
    for (int s = 0; s < 5; ++s) {
        const int h = 1 << s;
#pragma unroll
        for (int g = 0; g < 32; g += 2 * h)
#pragma unroll
            for (int e = 0; e < h; ++e) {
                float a = x[g + e], b = x[g + e + h];
                x[g + e]     = a + b;
                x[g + e + h] = a - b;
            }
    }
}

// returns x[lane^1] + sgn*x[lane]   (DPP quad_perm [1,0,3,2] = 0xB1, VALU-only)
__device__ __forceinline__ float bfly_xor1(float x, float sgn) {
    const int yi = __builtin_amdgcn_mov_dpp(__float_as_int(x), 0xB1, 0xF, 0xF, true);
    return __builtin_fmaf(sgn, x, __int_as_float(yi));
}

__global__ __launch_bounds__(BLOCK, 4)
void UpProjectFastHadamardTransform_80101140070867_kernel(
    const float* __restrict__ u, const int* __restrict__ idx,
    float* __restrict__ out, int nrows)
{
    __shared__ float lds[D];               // 4 quarters x 2048 f32 = 32 KB
    const int T = threadIdx.x;
    const int w = T >> 6;                  // wave id = output segment
    const int l = T & 63;

    float*  q  = lds + (w << 11);          // own quarter
    float4* q4 = (float4*)q;

    // ---- prologue (once per block): pack scatter descriptors ----
    // pk = phys word (11 bits) | signflip<<31,  sign = parity(w & (i>>11))
    // entry order: k = (j<<6) + l  (coalesced: 1 KB contiguous per load instr)
    int pk[16];
    {
        const int4* idx4 = (const int4*)idx;
#pragma unroll
        for (int j = 0; j < 4; ++j) {
            const int4 id = idx4[(j << 6) + l];
            auto PACK = [&](int i) {
                const int p = i & 2047, f = p >> 2;
                const int word = 4 * (f ^ ((f >> 3) & 7)) + (p & 3);
                const int sb = (i >> 11) & w;
                return word | (((sb ^ (sb >> 1)) & 1) << 31);
            };
            pk[4*j+0] = PACK(id.x); pk[4*j+1] = PACK(id.y);
            pk[4*j+2] = PACK(id.z); pk[4*j+3] = PACK(id.w);
        }
    }

    int r = blockIdx.x;
    const int stride = (int)gridDim.x;

    float4 uv[4];                          // current row's u (matches pk order)
    {
        const float4* u4 = (const float4*)(u + (size_t)r * K);
#pragma unroll
        for (int j = 0; j < 4; ++j) uv[j] = u4[(j << 6) + l];
    }

    const int   c1  = l & 7;               // swz xor for phase reads
    const float sgn = (l & 1) ? -1.f : 1.f;

    while (r < nrows) {
        // zero own quarter (wave-private; same-wave LDS ops are in order)
#pragma unroll
        for (int j = 0; j < 8; ++j)
            q4[(j << 6) + l] = make_float4(0.f, 0.f, 0.f, 0.f);

        // scatter: 16 signed atomics into own quarter (all 1024 row values)
#pragma unroll
        for (int j = 0; j < 4; ++j) {
            const int p0 = pk[4*j+0], p1 = pk[4*j+1],
                      p2 = pk[4*j+2], p3 = pk[4*j+3];
            atomicAdd(&q[p0 & 2047], __int_as_float(__float_as_int(uv[j].x) ^ (p0 & 0x80000000)));
            atomicAdd(&q[p1 & 2047], __int_as_float(__float_as_int(uv[j].y) ^ (p1 & 0x80000000)));
            atomicAdd(&q[p2 & 2047], __int_as_float(__float_as_int(uv[j].z) ^ (p2 & 0x80000000)));
            atomicAdd(&q[p3 & 2047], __int_as_float(__float_as_int(uv[j].w) ^ (p3 & 0x80000000)));
        }

        // prefetch next row's u (reuses uv regs; latency hidden under P1/P2)
        const int rn = r + stride;
        if (rn < nrows) {
            const float4* u4 = (const float4*)(u + (size_t)rn * K);
#pragma unroll
            for (int j = 0; j < 4; ++j) uv[j] = u4[(j << 6) + l];
        }

        float x[32];

        // ---- P1: read own quarter, fwht32 over b0..b4 ----
#pragma unroll
        for (int g = 0; g < 8; ++g) {
            const float4 a = q4[(l << 3) + (g ^ c1)];
            x[4*g+0] = a.x; x[4*g+1] = a.y; x[4*g+2] = a.z; x[4*g+3] = a.w;
        }
        fwht32(x);

        // ---- transposed write -> L1 (wave-private, conflict-free) ----
#pragma unroll
        for (int j = 0; j < 32; ++j) {
            const int f = (j << 4) + (l >> 2);
            q[4 * (f ^ ((2 * j + (l >> 5)) & 7)) + (l & 3)] = x[j];
        }

        // ---- P2: read back (same swz pattern), fwht32 over b5..b9 ----
#pragma unroll
        for (int g = 0; g < 8; ++g) {
            const float4 a = q4[(l << 3) + (g ^ c1)];
            x[4*g+0] = a.x; x[4*g+1] = a.y; x[4*g+2] = a.z; x[4*g+3] = a.w;
        }
        fwht32(x);

        // ---- b10 butterfly (DPP lane^1, pure VALU) + scaled NT store ----
        float* orow = out + (size_t)r * D + (w << 11) + ((l & 1) << 10) + (l >> 1);
#pragma unroll
        for (int m = 0; m < 32; ++m) {
            const float t = bfly_xor1(x[m], sgn);
            __builtin_nontemporal_store(t * SCALE, orow + (m << 5));
        }

        r = rn;
    }
}

extern "C" void kernel_launch(void* const* d_in, const int* in_sizes, int n_in,
                              void* d_out, int out_size, void* d_ws, size_t ws_size,
                              hipStream_t stream) {
    const float* u   = (const float*)d_in[0];
    const int*   idx = (const int*)d_in[1];
    float*       out = (float*)d_out;
    const int rows = in_sizes[0] / K;   // 8192
    const int grid = rows < GRID_MAX ? rows : GRID_MAX;
    hipLaunchKernelGGL(UpProjectFastHadamardTransform_80101140070867_kernel,
                       dim3(grid), dim3(BLOCK), 0, stream, u, idx, out, rows);
}